// Round 2
// baseline (592.243 us; speedup 1.0000x reference)
//
#include <hip/hip_runtime.h>
#include <cstdint>
#include <cstddef>

#define BATCH 32
#define HWDIM 1024
#define MROWS 32768   // BATCH*HWDIM
#define CDIM  1024    // feature dim
#define NCL   1024    // clusters

#define INV_TT 16.6666666f   // 1/0.06
#define INV_PT 8.33333333f   // 1/0.12

typedef __attribute__((ext_vector_type(8))) short bf16x8;
typedef __attribute__((ext_vector_type(4))) float f32x4;
typedef __attribute__((ext_vector_type(8))) unsigned short u16x8;
typedef __attribute__((ext_vector_type(4))) unsigned short u16x4;

// ---------- helpers ----------
__device__ __forceinline__ unsigned short f2bf(float f) {
  unsigned u = __float_as_uint(f);
  unsigned r = u + 0x7fffu + ((u >> 16) & 1u);   // round-to-nearest-even
  return (unsigned short)(r >> 16);
}
__device__ __forceinline__ float bf2f(unsigned short h) {
  return __uint_as_float(((unsigned)h) << 16);
}
// order-preserving float->uint key for atomicMax on floats (0 acts as -inf)
__device__ __forceinline__ unsigned fkey(float f) {
  unsigned u = __float_as_uint(f);
  return (u & 0x80000000u) ? ~u : (u | 0x80000000u);
}
__device__ __forceinline__ float funkey(unsigned k) {
  unsigned u = (k & 0x80000000u) ? (k & 0x7fffffffu) : ~k;
  return __uint_as_float(u);
}
__device__ __forceinline__ void async16(const unsigned short* g, unsigned short* l) {
  __builtin_amdgcn_global_load_lds(
      (const __attribute__((address_space(1))) unsigned int*)g,
      (__attribute__((address_space(3))) unsigned int*)l, 16, 0, 0);
}
__device__ __forceinline__ f32x4 mfma16(bf16x8 a, bf16x8 b, f32x4 c) {
  return __builtin_amdgcn_mfma_f32_16x16x32_bf16(a, b, c, 0, 0, 0);
}

#define BARX()   __builtin_amdgcn_s_barrier()
#define SCHED0() __builtin_amdgcn_sched_barrier(0)
#define VMCNT0() asm volatile("s_waitcnt vmcnt(0)" ::: "memory")
#define LGKM0()  asm volatile("s_waitcnt lgkmcnt(0)" ::: "memory")

// ---------- 1) normalize x rows, emit split-bf16 ----------
__global__ __launch_bounds__(256) void normx_kernel(
    const float* __restrict__ x, unsigned short* __restrict__ Ahi,
    unsigned short* __restrict__ Alo) {
  const int row = blockIdx.x;
  const int t = threadIdx.x;
  const float4 v = *(const float4*)(x + (size_t)row * CDIM + t * 4);
  float ss = v.x * v.x + v.y * v.y + v.z * v.z + v.w * v.w;
  for (int o = 32; o > 0; o >>= 1) ss += __shfl_xor(ss, o);
  __shared__ float red[4];
  const int wave = t >> 6, lane = t & 63;
  if (lane == 0) red[wave] = ss;
  __syncthreads();
  const float tot = red[0] + red[1] + red[2] + red[3];
  const float inv = 1.0f / fmaxf(sqrtf(tot), 1e-7f);
  float f0 = v.x * inv, f1 = v.y * inv, f2 = v.z * inv, f3 = v.w * inv;
  u16x4 hi, lo;
  hi[0] = f2bf(f0); lo[0] = f2bf(f0 - bf2f(hi[0]));
  hi[1] = f2bf(f1); lo[1] = f2bf(f1 - bf2f(hi[1]));
  hi[2] = f2bf(f2); lo[2] = f2bf(f2 - bf2f(hi[2]));
  hi[3] = f2bf(f3); lo[3] = f2bf(f3 - bf2f(hi[3]));
  *(u16x4*)(Ahi + (size_t)row * CDIM + t * 4) = hi;
  *(u16x4*)(Alo + (size_t)row * CDIM + t * 4) = lo;
}

// ---------- 2) split W into bf16 hi/lo ----------
__global__ __launch_bounds__(256) void convw_kernel(
    const float* __restrict__ Wm, unsigned short* __restrict__ Bhi,
    unsigned short* __restrict__ Blo) {
  const int row = blockIdx.x;
  const int t = threadIdx.x;
  const float4 v = *(const float4*)(Wm + (size_t)row * CDIM + t * 4);
  u16x4 hi, lo;
  hi[0] = f2bf(v.x); lo[0] = f2bf(v.x - bf2f(hi[0]));
  hi[1] = f2bf(v.y); lo[1] = f2bf(v.y - bf2f(hi[1]));
  hi[2] = f2bf(v.z); lo[2] = f2bf(v.z - bf2f(hi[2]));
  hi[3] = f2bf(v.w); lo[3] = f2bf(v.w - bf2f(hi[3]));
  *(u16x4*)(Bhi + (size_t)row * CDIM + t * 4) = hi;
  *(u16x4*)(Blo + (size_t)row * CDIM + t * 4) = lo;
}

// ---------- 3) split-bf16 GEMM + fused per-batch column max ----------
// 256x256 tile, BK=32, 8 waves (2m x 4n), per-wave 128x64 output, 3 MFMAs
// (hh+hl+lh). Double-buffered LDS (128 KiB), 4-phase K-step schedule:
// phase = {ds_read frags; [p0: stage all 8 global_load_lds -> other buf];
// s_barrier; lgkmcnt(0); sched_barrier(0); setprio(1) 24xMFMA setprio(0);
// s_barrier}. Single vmcnt(0) per K-step at phase-3 end (prefetch issued at
// phase 0 gets ~3 MFMA phases of cover).
// LDS chunk-rotation swizzle (proven 0-conflict): row r's logical 16B chunk
// j lives at physical slot (j + (r>>1)) & 3; staging pre-swizzles the GLOBAL
// source address and keeps the LDS destination linear (both-sides rule).
// XCD swizzle: nt fastest within an XCD chunk -> the 4 n-siblings of an
// m-tile are co-resident (A panel L2-shared; whole B panel = 4 MiB fits L2).
__global__ __launch_bounds__(512, 2) void gemm_kernel(
    const unsigned short* __restrict__ Ahi, const unsigned short* __restrict__ Alo,
    const unsigned short* __restrict__ Bhi, const unsigned short* __restrict__ Blo,
    float* __restrict__ C, unsigned* __restrict__ sk) {
  __shared__ unsigned short sAhi[2][8192], sAlo[2][8192];
  __shared__ unsigned short sBhi[2][8192], sBlo[2][8192];

  const int l = blockIdx.x;                 // 0..511
  const int idx = (l & 7) * 64 + (l >> 3);  // xcd-contiguous chunk
  const int m0 = (idx >> 2) * 256;          // 128 m-tiles
  const int n0 = (idx & 3) * 256;           // 4 n-tiles (fastest)
  const int tid = threadIdx.x;
  const int wave = tid >> 6;
  const int lane = tid & 63;
  const int fl = lane & 15;   // fragment row/col
  const int q = lane >> 4;    // quad: k-offset q*8 (inputs), row-offset q*4 (C/D)
  const int wr = (wave >> 2) * 128;   // 0 or 128
  const int wc = (wave & 3) * 64;     // 0,64,128,192

  // staging coords: thread fills 16B phys slot (tid&3) of local row (tid>>2)
  const int srow = tid >> 2;          // 0..127
  const int pph = tid & 3;
  const int r0 = srow, r1 = 128 + srow;
  const int j0 = (pph - (r0 >> 1)) & 3;   // logical chunk at my phys slot
  const int j1 = (pph - (r1 >> 1)) & 3;
  const size_t aoff0 = (size_t)(m0 + r0) * CDIM + j0 * 8;
  const size_t aoff1 = (size_t)(m0 + r1) * CDIM + j1 * 8;
  const size_t boff0 = (size_t)(n0 + r0) * CDIM + j0 * 8;
  const size_t boff1 = (size_t)(n0 + r1) * CDIM + j1 * 8;
  const int ld0 = (0 + (wave << 4)) * 32;    // wave-uniform LDS dest (rows 0-127)
  const int ld1 = (128 + (wave << 4)) * 32;  // rows 128-255

  f32x4 acc[8][4];
#pragma unroll
  for (int i = 0; i < 8; i++)
#pragma unroll
    for (int j = 0; j < 4; j++) { f32x4 z = {0.f, 0.f, 0.f, 0.f}; acc[i][j] = z; }

#define STAGE_ALL(k, b) do {                         \
    async16(Ahi + aoff0 + (k), &sAhi[b][ld0]);       \
    async16(Alo + aoff0 + (k), &sAlo[b][ld0]);       \
    async16(Ahi + aoff1 + (k), &sAhi[b][ld1]);       \
    async16(Alo + aoff1 + (k), &sAlo[b][ld1]);       \
    async16(Bhi + boff0 + (k), &sBhi[b][ld0]);       \
    async16(Blo + boff0 + (k), &sBlo[b][ld0]);       \
    async16(Bhi + boff1 + (k), &sBhi[b][ld1]);       \
    async16(Blo + boff1 + (k), &sBlo[b][ld1]);       \
  } while (0)

  // rows ra0 and ra0+16 share the phys rotation ((r>>1) differs by 8 == 0 mod 4)
#define READ_A(p) do {                                   \
    const int ra0 = wr + 2 * (p) * 16 + fl;              \
    const int pa0 = ((q + (ra0 >> 1)) & 3) * 8;          \
    ah0 = *(const bf16x8*)&sAhi[cur][ra0 * 32 + pa0];    \
    al0 = *(const bf16x8*)&sAlo[cur][ra0 * 32 + pa0];    \
    const int ra1 = ra0 + 16;                            \
    ah1 = *(const bf16x8*)&sAhi[cur][ra1 * 32 + pa0];    \
    al1 = *(const bf16x8*)&sAlo[cur][ra1 * 32 + pa0];    \
  } while (0)

#define MFMA_P(p) do {                                             \
    __builtin_amdgcn_s_setprio(1);                                 \
    _Pragma("unroll")                                              \
    for (int nj = 0; nj < 4; ++nj) {                               \
      acc[2*(p)][nj]   = mfma16(ah0, bh[nj], acc[2*(p)][nj]);      \
      acc[2*(p)][nj]   = mfma16(ah0, bl[nj], acc[2*(p)][nj]);      \
      acc[2*(p)][nj]   = mfma16(al0, bh[nj], acc[2*(p)][nj]);      \
      acc[2*(p)+1][nj] = mfma16(ah1, bh[nj], acc[2*(p)+1][nj]);    \
      acc[2*(p)+1][nj] = mfma16(ah1, bl[nj], acc[2*(p)+1][nj]);    \
      acc[2*(p)+1][nj] = mfma16(al1, bh[nj], acc[2*(p)+1][nj]);    \
    }                                                              \
    __builtin_amdgcn_s_setprio(0);                                 \
  } while (0)

  // prologue: stage K-step 0 into buf 0
  STAGE_ALL((size_t)0, 0);
  VMCNT0();
  BARX();

  bf16x8 bh[4], bl[4], ah0, al0, ah1, al1;

  for (int t = 0; t < 32; ++t) {
    const int cur = t & 1;
    const int nxt = cur ^ 1;

    // ---- phase 0: B frags + A pair0; prefetch next K-step ----
#pragma unroll
    for (int nj = 0; nj < 4; ++nj) {
      const int rb = wc + nj * 16 + fl;
      const int pb = ((q + (rb >> 1)) & 3) * 8;
      bh[nj] = *(const bf16x8*)&sBhi[cur][rb * 32 + pb];
      bl[nj] = *(const bf16x8*)&sBlo[cur][rb * 32 + pb];
    }
    READ_A(0);
    if (t < 31) {                       // uniform branch; no stage on last step
      const size_t kn = (size_t)(t + 1) * 32;
      STAGE_ALL(kn, nxt);
    }
    BARX(); LGKM0(); SCHED0();
    MFMA_P(0);
    BARX();
    // ---- phase 1 ----
    READ_A(1);
    BARX(); LGKM0(); SCHED0();
    MFMA_P(1);
    BARX();
    // ---- phase 2 ----
    READ_A(2);
    BARX(); LGKM0(); SCHED0();
    MFMA_P(2);
    BARX();
    // ---- phase 3 ----
    READ_A(3);
    BARX(); LGKM0(); SCHED0();
    MFMA_P(3);
    VMCNT0();   // next-step loads landed; only vmem wait in the loop
    BARX();
  }

  // fused column max of this tile (per batch); 256-row tile is within one batch
  const int batch = m0 >> 10;
#pragma unroll
  for (int nj = 0; nj < 4; ++nj) {
    float m = -3.4e38f;
#pragma unroll
    for (int mi = 0; mi < 8; ++mi)
#pragma unroll
      for (int r = 0; r < 4; ++r) m = fmaxf(m, acc[mi][nj][r]);
    m = fmaxf(m, __shfl_xor(m, 16));
    m = fmaxf(m, __shfl_xor(m, 32));
    if (q == 0) atomicMax(&sk[batch * NCL + n0 + wc + nj * 16 + fl], fkey(m));
  }

  // epilogue: C/D layout col=lane&15, row=q*4+reg
#pragma unroll
  for (int mi = 0; mi < 8; ++mi)
#pragma unroll
    for (int nj = 0; nj < 4; ++nj)
#pragma unroll
      for (int r = 0; r < 4; ++r) {
        const int gm = m0 + wr + mi * 16 + q * 4 + r;
        const int gn = n0 + wc + nj * 16 + fl;
        C[(size_t)gm * NCL + gn] = acc[mi][nj][r];
      }
#undef STAGE_ALL
#undef READ_A
#undef MFMA_P
}

// ---------- 4) E = exp(l/0.06 + 50 - shift) -> bf16; S1 = colsum(E) ----------
__global__ __launch_bounds__(256) void expcs_kernel(
    const float* __restrict__ L, const unsigned* __restrict__ sk,
    unsigned short* __restrict__ E, float* __restrict__ S1) {
  const int b = blockIdx.x >> 4, rc = blockIdx.x & 15, t = threadIdx.x;
  const size_t base = ((size_t)b * HWDIM + rc * 64) * NCL + t * 4;
  const unsigned* kp = sk + b * NCL + t * 4;
  const float o0 = 50.f - funkey(kp[0]) * INV_TT;
  const float o1 = 50.f - funkey(kp[1]) * INV_TT;
  const float o2 = 50.f - funkey(kp[2]) * INV_TT;
  const float o3 = 50.f - funkey(kp[3]) * INV_TT;
  float s0 = 0, s1 = 0, s2 = 0, s3 = 0;
  for (int r = 0; r < 64; ++r) {
    float4 v = *(const float4*)(L + base + (size_t)r * NCL);
    float e0 = __expf(v.x * INV_TT + o0);
    float e1 = __expf(v.y * INV_TT + o1);
    float e2 = __expf(v.z * INV_TT + o2);
    float e3 = __expf(v.w * INV_TT + o3);
    s0 += e0; s1 += e1; s2 += e2; s3 += e3;
    u16x4 ev; ev[0] = f2bf(e0); ev[1] = f2bf(e1); ev[2] = f2bf(e2); ev[3] = f2bf(e3);
    *(u16x4*)(E + base + (size_t)r * NCL) = ev;
  }
  float* d = S1 + b * NCL + t * 4;
  atomicAdd(d + 0, s0); atomicAdd(d + 1, s1);
  atomicAdd(d + 2, s2); atomicAdd(d + 3, s3);
}

// ---------- 5) fused T_i (row sums) + S_{i+1} (col sums) ----------
__global__ __launch_bounds__(256) void fused_ts_kernel(
    const unsigned short* __restrict__ E, const float* __restrict__ S1,
    const float* __restrict__ S2, const float* __restrict__ S3,
    const float* __restrict__ T1p, const float* __restrict__ T2p, int nS,
    float* __restrict__ Tout, float* __restrict__ Sout) {
  __shared__ float cs[NCL];
  __shared__ float rr_s[64];
  const int b = blockIdx.x >> 4, rc = blockIdx.x & 15, t = threadIdx.x;
  {
    const int k = t * 4;
    float4 s1 = *(const float4*)(S1 + b * NCL + k);
    float c0 = 1.f / (s1.x + 1e-8f), c1 = 1.f / (s1.y + 1e-8f);
    float c2 = 1.f / (s1.z + 1e-8f), c3 = 1.f / (s1.w + 1e-8f);
    if (nS >= 2) {
      float4 s2 = *(const float4*)(S2 + b * NCL + k);
      c0 = c0 / (c0 * s2.x + 1e-8f); c1 = c1 / (c1 * s2.y + 1e-8f);
      c2 = c2 / (c2 * s2.z + 1e-8f); c3 = c3 / (c3 * s2.w + 1e-8f);
    }
    if (nS >= 3) {
      float4 s3 = *(const float4*)(S3 + b * NCL + k);
      c0 = c0 / (c0 * s3.x + 1e-8f); c1 = c1 / (c1 * s3.y + 1e-8f);
      c2 = c2 / (c2 * s3.z + 1e-8f); c3 = c3 / (c3 * s3.w + 1e-8f);
    }
    cs[k] = c0; cs[k + 1] = c1; cs[k + 2] = c2; cs[k + 3] = c3;
  }
  __syncthreads();
  const int wave = t >> 6, lane = t & 63;
  const int row0 = b * HWDIM + rc * 64;
  for (int rr = wave; rr < 64; rr += 4) {
    const int row = row0 + rr;
    const unsigned short* ep = E + (size_t)row * NCL + lane * 16;
    u16x8 e0 = *(const u16x8*)ep;
    u16x8 e1 = *(const u16x8*)(ep + 8);
    const float* cp = cs + lane * 16;
    float sum = 0.f;
#pragma unroll
    for (int j = 0; j < 8; j++) sum += bf2f(e0[j]) * cp[j];
#pragma unroll
    for (int j = 0; j < 8; j++) sum += bf2f(e1[j]) * cp[8 + j];
    for (int o = 32; o > 0; o >>= 1) sum += __shfl_xor(sum, o);
    if (lane == 0) {
      Tout[row] = sum;
      if (nS < 3) {
        float r;
        if (nS == 1) {
          r = 1.f / (sum + 1e-8f);
        } else {  // nS == 2
          r = 1.f / (T1p[row] + 1e-8f);
          r = r / (r * sum + 1e-8f);
        }
        rr_s[rr] = r;
      }
    }
  }
  if (nS >= 3) return;
  __syncthreads();
  float a0 = 0, a1 = 0, a2 = 0, a3 = 0;
  const unsigned short* basep = E + (size_t)row0 * NCL + t * 4;
  for (int rr = 0; rr < 64; ++rr) {
    const float rv = rr_s[rr];
    u16x4 ev = *(const u16x4*)(basep + (size_t)rr * NCL);
    a0 += bf2f(ev[0]) * rv; a1 += bf2f(ev[1]) * rv;
    a2 += bf2f(ev[2]) * rv; a3 += bf2f(ev[3]) * rv;
  }
  float* d = Sout + b * NCL + t * 4;
  atomicAdd(d + 0, a0); atomicAdd(d + 1, a1);
  atomicAdd(d + 2, a2); atomicAdd(d + 3, a3);
  (void)T2p;
}

// ---------- 6) final: assignments (in-place over logits) + loss ----------
__global__ __launch_bounds__(256) void final_kernel(
    float* __restrict__ IO, const unsigned* __restrict__ sk,
    const float* __restrict__ S1, const float* __restrict__ S2,
    const float* __restrict__ S3, const float* __restrict__ T1,
    const float* __restrict__ T2, const float* __restrict__ T3,
    float* __restrict__ lossout) {
  __shared__ float cs[NCL];
  __shared__ float offs[NCL];
  __shared__ float lred[4];
  const int b = blockIdx.x >> 4, rc = blockIdx.x & 15, t = threadIdx.x;
  {
    const int k = t * 4;
    float4 s1 = *(const float4*)(S1 + b * NCL + k);
    float4 s2 = *(const float4*)(S2 + b * NCL + k);
    float4 s3 = *(const float4*)(S3 + b * NCL + k);
    float c;
    c = 1.f / (s1.x + 1e-8f); c = c / (c * s2.x + 1e-8f); c = c / (c * s3.x + 1e-8f); cs[k] = c;
    c = 1.f / (s1.y + 1e-8f); c = c / (c * s2.y + 1e-8f); c = c / (c * s3.y + 1e-8f); cs[k + 1] = c;
    c = 1.f / (s1.z + 1e-8f); c = c / (c * s2.z + 1e-8f); c = c / (c * s3.z + 1e-8f); cs[k + 2] = c;
    c = 1.f / (s1.w + 1e-8f); c = c / (c * s2.w + 1e-8f); c = c / (c * s3.w + 1e-8f); cs[k + 3] = c;
    const unsigned* kp = sk + b * NCL + k;
    offs[k]     = 50.f - funkey(kp[0]) * INV_TT;
    offs[k + 1] = 50.f - funkey(kp[1]) * INV_TT;
    offs[k + 2] = 50.f - funkey(kp[2]) * INV_TT;
    offs[k + 3] = 50.f - funkey(kp[3]) * INV_TT;
  }
  __syncthreads();
  const int wave = t >> 6, lane = t & 63;
  float wsum = 0.f;
  for (int rr = wave; rr < 64; rr += 4) {
    const int row = b * HWDIM + rc * 64 + rr;
    float r3;
    {
      float r = 1.f / (T1[row] + 1e-8f);
      r = r / (r * T2[row] + 1e-8f);
      r = r / (r * T3[row] + 1e-8f);
      r3 = r;
    }
    float* p = IO + (size_t)row * NCL + lane * 16;
    float4 v0 = *(const float4*)(p);
    float4 v1 = *(const float4*)(p + 4);
    float4 v2 = *(const float4*)(p + 8);
    float4 v3 = *(const float4*)(p + 12);
    float lv[16] = {v0.x, v0.y, v0.z, v0.w, v1.x, v1.y, v1.z, v1.w,
                    v2.x, v2.y, v2.z, v2.w, v3.x, v3.y, v3.z, v3.w};
    float mx = lv[0];
#pragma unroll
    for (int j = 1; j < 16; j++) mx = fmaxf(mx, lv[j]);
    for (int o = 32; o > 0; o >>= 1) mx = fmaxf(mx, __shfl_xor(mx, o));
    const float mp = mx * INV_PT;
    float esum = 0.f, tp = 0.f, ts = 0.f;
    float tg[16];
    const float* cp = cs + lane * 16;
    const float* op = offs + lane * 16;
#pragma unroll
    for (int j = 0; j < 16; j++) {
      const float Ev = __expf(lv[j] * INV_TT + op[j]);
      const float g = Ev * cp[j] * r3;
      tg[j] = g;
      const float pd = lv[j] * INV_PT;
      esum += __expf(pd - mp);
      tp += g * pd;
      ts += g;
    }
    for (int o = 32; o > 0; o >>= 1) {
      esum += __shfl_xor(esum, o);
      tp += __shfl_xor(tp, o);
      ts += __shfl_xor(ts, o);
    }
    if (lane == 0) wsum += tp - (mp + logf(esum)) * ts;
    float4 w0 = {tg[0], tg[1], tg[2], tg[3]};
    float4 w1 = {tg[4], tg[5], tg[6], tg[7]};
    float4 w2 = {tg[8], tg[9], tg[10], tg[11]};
    float4 w3 = {tg[12], tg[13], tg[14], tg[15]};
    *(float4*)(p) = w0;
    *(float4*)(p + 4) = w1;
    *(float4*)(p + 8) = w2;
    *(float4*)(p + 12) = w3;
  }
  if (lane == 0) lred[wave] = wsum;
  __syncthreads();
  if (t == 0) {
    const float bl = lred[0] + lred[1] + lred[2] + lred[3];
    atomicAdd(lossout, bl * (-1.f / 32768.f));
  }
}

// ---------- launch ----------
extern "C" void kernel_launch(void* const* d_in, const int* in_sizes, int n_in,
                              void* d_out, int out_size, void* d_ws, size_t ws_size,
                              hipStream_t stream) {
  const float* x = (const float*)d_in[0];
  const float* W = (const float*)d_in[1];
  float* out = (float*)d_out;
  char* ws = (char*)d_ws;

  const size_t MiB = 1024 * 1024;
  unsigned short* Ahi = (unsigned short*)(ws);                 // 64 MiB
  unsigned short* Alo = (unsigned short*)(ws + 64 * MiB);      // 64 MiB
  unsigned short* Bhi = (unsigned short*)(ws + 128 * MiB);     // 2 MiB
  unsigned short* Blo = (unsigned short*)(ws + 130 * MiB);     // 2 MiB
  unsigned short* E   = (unsigned short*)(ws);                 // aliases Ahi (dead after GEMM)
  char* small = ws + 132 * MiB;
  unsigned* sk = (unsigned*)(small);                           // 128 KiB (zero = -inf key)
  float* S1 = (float*)(small + 128 * 1024);
  float* S2 = (float*)(small + 256 * 1024);
  float* S3 = (float*)(small + 384 * 1024);
  float* T1 = (float*)(small + 512 * 1024);
  float* T2 = (float*)(small + 640 * 1024);
  float* T3 = (float*)(small + 768 * 1024);

  float* logits = out;               // first 33554432 floats of d_out used as scratch
  float* lossp = out + 33554432;

  hipMemsetAsync(small, 0, 896 * 1024, stream);
  hipMemsetAsync(lossp, 0, 4, stream);

  normx_kernel<<<MROWS, 256, 0, stream>>>(x, Ahi, Alo);
  convw_kernel<<<NCL, 256, 0, stream>>>(W, Bhi, Blo);
  gemm_kernel<<<512, 512, 0, stream>>>(Ahi, Alo, Bhi, Blo, logits, sk);
  expcs_kernel<<<512, 256, 0, stream>>>(logits, sk, E, S1);
  fused_ts_kernel<<<512, 256, 0, stream>>>(E, S1, S2, S3, T1, T2, 1, T1, S2);
  fused_ts_kernel<<<512, 256, 0, stream>>>(E, S1, S2, S3, T1, T2, 2, T2, S3);
  fused_ts_kernel<<<512, 256, 0, stream>>>(E, S1, S2, S3, T1, T2, 3, T3, nullptr);
  final_kernel<<<512, 256, 0, stream>>>(logits, sk, S1, S2, S3, T1, T2, T3, lossp);
}

// Round 3
// 565.485 us; speedup vs baseline: 1.0473x; 1.0473x over previous
//
#include <hip/hip_runtime.h>
#include <cstdint>
#include <cstddef>

#define BATCH 32
#define HWDIM 1024
#define MROWS 32768   // BATCH*HWDIM
#define CDIM  1024    // feature dim
#define NCL   1024    // clusters

#define INV_TT 16.6666666f   // 1/0.06
#define INV_PT 8.33333333f   // 1/0.12

typedef __attribute__((ext_vector_type(8))) short bf16x8;
typedef __attribute__((ext_vector_type(4))) float f32x4;
typedef __attribute__((ext_vector_type(8))) unsigned short u16x8;
typedef __attribute__((ext_vector_type(4))) unsigned short u16x4;

// ---------- helpers ----------
__device__ __forceinline__ unsigned short f2bf(float f) {
  unsigned u = __float_as_uint(f);
  unsigned r = u + 0x7fffu + ((u >> 16) & 1u);   // round-to-nearest-even
  return (unsigned short)(r >> 16);
}
__device__ __forceinline__ float bf2f(unsigned short h) {
  return __uint_as_float(((unsigned)h) << 16);
}
// order-preserving float->uint key for atomicMax on floats (0 acts as -inf)
__device__ __forceinline__ unsigned fkey(float f) {
  unsigned u = __float_as_uint(f);
  return (u & 0x80000000u) ? ~u : (u | 0x80000000u);
}
__device__ __forceinline__ float funkey(unsigned k) {
  unsigned u = (k & 0x80000000u) ? (k & 0x7fffffffu) : ~k;
  return __uint_as_float(u);
}
__device__ __forceinline__ void async16(const unsigned short* g, unsigned short* l) {
  __builtin_amdgcn_global_load_lds(
      (const __attribute__((address_space(1))) unsigned int*)g,
      (__attribute__((address_space(3))) unsigned int*)l, 16, 0, 0);
}
__device__ __forceinline__ f32x4 mfma16(bf16x8 a, bf16x8 b, f32x4 c) {
  return __builtin_amdgcn_mfma_f32_16x16x32_bf16(a, b, c, 0, 0, 0);
}

#define BARX()   __builtin_amdgcn_s_barrier()
#define SCHED0() __builtin_amdgcn_sched_barrier(0)
#define VMCNT0() asm volatile("s_waitcnt vmcnt(0)" ::: "memory")
#define VMCNT8() asm volatile("s_waitcnt vmcnt(8)" ::: "memory")
#define LGKM0()  asm volatile("s_waitcnt lgkmcnt(0)" ::: "memory")

// ---------- 1) normalize x rows, emit split-bf16 ----------
__global__ __launch_bounds__(256) void normx_kernel(
    const float* __restrict__ x, unsigned short* __restrict__ Ahi,
    unsigned short* __restrict__ Alo) {
  const int row = blockIdx.x;
  const int t = threadIdx.x;
  const float4 v = *(const float4*)(x + (size_t)row * CDIM + t * 4);
  float ss = v.x * v.x + v.y * v.y + v.z * v.z + v.w * v.w;
  for (int o = 32; o > 0; o >>= 1) ss += __shfl_xor(ss, o);
  __shared__ float red[4];
  const int wave = t >> 6, lane = t & 63;
  if (lane == 0) red[wave] = ss;
  __syncthreads();
  const float tot = red[0] + red[1] + red[2] + red[3];
  const float inv = 1.0f / fmaxf(sqrtf(tot), 1e-7f);
  float f0 = v.x * inv, f1 = v.y * inv, f2 = v.z * inv, f3 = v.w * inv;
  u16x4 hi, lo;
  hi[0] = f2bf(f0); lo[0] = f2bf(f0 - bf2f(hi[0]));
  hi[1] = f2bf(f1); lo[1] = f2bf(f1 - bf2f(hi[1]));
  hi[2] = f2bf(f2); lo[2] = f2bf(f2 - bf2f(hi[2]));
  hi[3] = f2bf(f3); lo[3] = f2bf(f3 - bf2f(hi[3]));
  *(u16x4*)(Ahi + (size_t)row * CDIM + t * 4) = hi;
  *(u16x4*)(Alo + (size_t)row * CDIM + t * 4) = lo;
}

// ---------- 2) split W into bf16 hi/lo ----------
__global__ __launch_bounds__(256) void convw_kernel(
    const float* __restrict__ Wm, unsigned short* __restrict__ Bhi,
    unsigned short* __restrict__ Blo) {
  const int row = blockIdx.x;
  const int t = threadIdx.x;
  const float4 v = *(const float4*)(Wm + (size_t)row * CDIM + t * 4);
  u16x4 hi, lo;
  hi[0] = f2bf(v.x); lo[0] = f2bf(v.x - bf2f(hi[0]));
  hi[1] = f2bf(v.y); lo[1] = f2bf(v.y - bf2f(hi[1]));
  hi[2] = f2bf(v.z); lo[2] = f2bf(v.z - bf2f(hi[2]));
  hi[3] = f2bf(v.w); lo[3] = f2bf(v.w - bf2f(hi[3]));
  *(u16x4*)(Bhi + (size_t)row * CDIM + t * 4) = hi;
  *(u16x4*)(Blo + (size_t)row * CDIM + t * 4) = lo;
}

// ---------- 3) split-bf16 GEMM + fused per-batch column max ----------
// 256x256 tile, BK=32, 8 waves (2m x 4n), per-wave 128x64, 3 MFMAs (hh+hl+lh).
// T3+T4: 4-phase K-step with COUNTED vmcnt (2-deep prefetch):
//   A ring 3-deep (96 KiB), B ring 2-deep (64 KiB) = 160 KiB LDS.
//   B is fully consumed in phase 0, so Bbuf[t&1] frees a whole K-step early.
//   step t p0: issue A(t+2); p1: issue B(t+2); p3 end: vmcnt(8) -- keeps the
//   8 loads of step t+2 in flight, forces step t+1's landed. A cover ~7
//   phases (~1700cy), B cover ~2 K-steps -- both > ~900cy HBM-miss latency.
// LDS chunk-rotation swizzle (0-conflict, proven): row r's logical 16B chunk
// j at physical slot (j + (r>>1)) & 3; pre-swizzled GLOBAL source, linear
// LDS dest (both-sides rule). XCD swizzle: nt fastest -> A-panel L2 reuse.
__global__ __launch_bounds__(512, 2) void gemm_kernel(
    const unsigned short* __restrict__ Ahi, const unsigned short* __restrict__ Alo,
    const unsigned short* __restrict__ Bhi, const unsigned short* __restrict__ Blo,
    float* __restrict__ C, unsigned* __restrict__ sk) {
  __shared__ unsigned short sAhi[3][8192], sAlo[3][8192];
  __shared__ unsigned short sBhi[2][8192], sBlo[2][8192];

  const int l = blockIdx.x;                 // 0..511
  const int idx = (l & 7) * 64 + (l >> 3);  // xcd-contiguous chunk
  const int m0 = (idx >> 2) * 256;          // 128 m-tiles
  const int n0 = (idx & 3) * 256;           // 4 n-tiles (fastest)
  const int tid = threadIdx.x;
  const int wave = tid >> 6;
  const int lane = tid & 63;
  const int fl = lane & 15;   // fragment row/col
  const int q = lane >> 4;    // quad: k-offset q*8 (inputs), row-offset q*4 (C/D)
  const int wr = (wave >> 2) * 128;   // 0 or 128
  const int wc = (wave & 3) * 64;     // 0,64,128,192

  // staging coords: thread fills 16B phys slot (tid&3) of local row (tid>>2)
  const int srow = tid >> 2;          // 0..127
  const int pph = tid & 3;
  const int r0 = srow, r1 = 128 + srow;
  const int j0 = (pph - (r0 >> 1)) & 3;   // logical chunk at my phys slot
  const int j1 = (pph - (r1 >> 1)) & 3;
  const size_t aoff0 = (size_t)(m0 + r0) * CDIM + j0 * 8;
  const size_t aoff1 = (size_t)(m0 + r1) * CDIM + j1 * 8;
  const size_t boff0 = (size_t)(n0 + r0) * CDIM + j0 * 8;
  const size_t boff1 = (size_t)(n0 + r1) * CDIM + j1 * 8;
  const int ld0 = (0 + (wave << 4)) * 32;    // wave-uniform LDS dest (rows 0-127)
  const int ld1 = (128 + (wave << 4)) * 32;  // rows 128-255

  f32x4 acc[8][4];
#pragma unroll
  for (int i = 0; i < 8; i++)
#pragma unroll
    for (int j = 0; j < 4; j++) { f32x4 z = {0.f, 0.f, 0.f, 0.f}; acc[i][j] = z; }

#define STAGE_A(k, b) do {                           \
    async16(Ahi + aoff0 + (k), &sAhi[b][ld0]);       \
    async16(Alo + aoff0 + (k), &sAlo[b][ld0]);       \
    async16(Ahi + aoff1 + (k), &sAhi[b][ld1]);       \
    async16(Alo + aoff1 + (k), &sAlo[b][ld1]);       \
  } while (0)
#define STAGE_B(k, b) do {                           \
    async16(Bhi + boff0 + (k), &sBhi[b][ld0]);       \
    async16(Blo + boff0 + (k), &sBlo[b][ld0]);       \
    async16(Bhi + boff1 + (k), &sBhi[b][ld1]);       \
    async16(Blo + boff1 + (k), &sBlo[b][ld1]);       \
  } while (0)

  // rows ra0 and ra0+16 share the phys rotation ((r>>1) differs by 8 == 0 mod 4)
#define READ_A(p) do {                                   \
    const int ra0 = wr + 2 * (p) * 16 + fl;              \
    const int pa0 = ((q + (ra0 >> 1)) & 3) * 8;          \
    ah0 = *(const bf16x8*)&sAhi[ca][ra0 * 32 + pa0];     \
    al0 = *(const bf16x8*)&sAlo[ca][ra0 * 32 + pa0];     \
    const int ra1 = ra0 + 16;                            \
    ah1 = *(const bf16x8*)&sAhi[ca][ra1 * 32 + pa0];     \
    al1 = *(const bf16x8*)&sAlo[ca][ra1 * 32 + pa0];     \
  } while (0)

#define MFMA_P(p) do {                                             \
    __builtin_amdgcn_s_setprio(1);                                 \
    _Pragma("unroll")                                              \
    for (int nj = 0; nj < 4; ++nj) {                               \
      acc[2*(p)][nj]   = mfma16(ah0, bh[nj], acc[2*(p)][nj]);      \
      acc[2*(p)][nj]   = mfma16(ah0, bl[nj], acc[2*(p)][nj]);      \
      acc[2*(p)][nj]   = mfma16(al0, bh[nj], acc[2*(p)][nj]);      \
      acc[2*(p)+1][nj] = mfma16(ah1, bh[nj], acc[2*(p)+1][nj]);    \
      acc[2*(p)+1][nj] = mfma16(ah1, bl[nj], acc[2*(p)+1][nj]);    \
      acc[2*(p)+1][nj] = mfma16(al1, bh[nj], acc[2*(p)+1][nj]);    \
    }                                                              \
    __builtin_amdgcn_s_setprio(0);                                 \
  } while (0)

  // prologue: stage steps 0 and 1; wait only for step 0 (vmcnt(8))
  STAGE_A((size_t)0, 0);
  STAGE_B((size_t)0, 0);
  STAGE_A((size_t)32, 1);
  STAGE_B((size_t)32, 1);
  VMCNT8();
  BARX();

  bf16x8 bh[4], bl[4], ah0, al0, ah1, al1;
  int ca = 0;   // A buf for step t   (t % 3)
  int pa = 2;   // A buf for step t+2 ((t+2) % 3)

  for (int t = 0; t < 32; ++t) {
    const int cb = t & 1;               // B buf for step t (and dest for t+2)

    // ---- phase 0: B frags + A pair0; prefetch A(t+2) ----
#pragma unroll
    for (int nj = 0; nj < 4; ++nj) {
      const int rb = wc + nj * 16 + fl;
      const int pb = ((q + (rb >> 1)) & 3) * 8;
      bh[nj] = *(const bf16x8*)&sBhi[cb][rb * 32 + pb];
      bl[nj] = *(const bf16x8*)&sBlo[cb][rb * 32 + pb];
    }
    READ_A(0);
    if (t < 30) {
      const size_t kn = (size_t)(t + 2) * 32;
      STAGE_A(kn, pa);
    }
    BARX(); LGKM0(); SCHED0();
    MFMA_P(0);
    BARX();
    // ---- phase 1: prefetch B(t+2) (Bbuf[cb] freed by phase-0 barrier) ----
    READ_A(1);
    if (t < 30) {
      const size_t kn = (size_t)(t + 2) * 32;
      STAGE_B(kn, cb);
    }
    BARX(); LGKM0(); SCHED0();
    MFMA_P(1);
    BARX();
    // ---- phase 2 ----
    READ_A(2);
    BARX(); LGKM0(); SCHED0();
    MFMA_P(2);
    BARX();
    // ---- phase 3 ----
    READ_A(3);
    BARX(); LGKM0(); SCHED0();
    MFMA_P(3);
    if (t < 30) VMCNT8();   // counted: step t+2 loads stay in flight
    else        VMCNT0();   // tail drain
    BARX();

    ca = (ca == 2) ? 0 : ca + 1;
    pa = (pa == 2) ? 0 : pa + 1;
  }

  // fused column max of this tile (per batch); 256-row tile is within one batch
  const int batch = m0 >> 10;
#pragma unroll
  for (int nj = 0; nj < 4; ++nj) {
    float m = -3.4e38f;
#pragma unroll
    for (int mi = 0; mi < 8; ++mi)
#pragma unroll
      for (int r = 0; r < 4; ++r) m = fmaxf(m, acc[mi][nj][r]);
    m = fmaxf(m, __shfl_xor(m, 16));
    m = fmaxf(m, __shfl_xor(m, 32));
    if (q == 0) atomicMax(&sk[batch * NCL + n0 + wc + nj * 16 + fl], fkey(m));
  }

  // epilogue: C/D layout col=lane&15, row=q*4+reg
#pragma unroll
  for (int mi = 0; mi < 8; ++mi)
#pragma unroll
    for (int nj = 0; nj < 4; ++nj)
#pragma unroll
      for (int r = 0; r < 4; ++r) {
        const int gm = m0 + wr + mi * 16 + q * 4 + r;
        const int gn = n0 + wc + nj * 16 + fl;
        C[(size_t)gm * NCL + gn] = acc[mi][nj][r];
      }
#undef STAGE_A
#undef STAGE_B
#undef READ_A
#undef MFMA_P
}

// ---------- 4) E = exp(l/0.06 + 50 - shift) -> bf16; S1 = colsum(E) ----------
__global__ __launch_bounds__(256) void expcs_kernel(
    const float* __restrict__ L, const unsigned* __restrict__ sk,
    unsigned short* __restrict__ E, float* __restrict__ S1) {
  const int b = blockIdx.x >> 4, rc = blockIdx.x & 15, t = threadIdx.x;
  const size_t base = ((size_t)b * HWDIM + rc * 64) * NCL + t * 4;
  const unsigned* kp = sk + b * NCL + t * 4;
  const float o0 = 50.f - funkey(kp[0]) * INV_TT;
  const float o1 = 50.f - funkey(kp[1]) * INV_TT;
  const float o2 = 50.f - funkey(kp[2]) * INV_TT;
  const float o3 = 50.f - funkey(kp[3]) * INV_TT;
  float s0 = 0, s1 = 0, s2 = 0, s3 = 0;
  for (int r = 0; r < 64; ++r) {
    float4 v = *(const float4*)(L + base + (size_t)r * NCL);
    float e0 = __expf(v.x * INV_TT + o0);
    float e1 = __expf(v.y * INV_TT + o1);
    float e2 = __expf(v.z * INV_TT + o2);
    float e3 = __expf(v.w * INV_TT + o3);
    s0 += e0; s1 += e1; s2 += e2; s3 += e3;
    u16x4 ev; ev[0] = f2bf(e0); ev[1] = f2bf(e1); ev[2] = f2bf(e2); ev[3] = f2bf(e3);
    *(u16x4*)(E + base + (size_t)r * NCL) = ev;
  }
  float* d = S1 + b * NCL + t * 4;
  atomicAdd(d + 0, s0); atomicAdd(d + 1, s1);
  atomicAdd(d + 2, s2); atomicAdd(d + 3, s3);
}

// ---------- 5) fused T_i (row sums) + S_{i+1} (col sums) ----------
__global__ __launch_bounds__(256) void fused_ts_kernel(
    const unsigned short* __restrict__ E, const float* __restrict__ S1,
    const float* __restrict__ S2, const float* __restrict__ S3,
    const float* __restrict__ T1p, const float* __restrict__ T2p, int nS,
    float* __restrict__ Tout, float* __restrict__ Sout) {
  __shared__ float cs[NCL];
  __shared__ float rr_s[64];
  const int b = blockIdx.x >> 4, rc = blockIdx.x & 15, t = threadIdx.x;
  {
    const int k = t * 4;
    float4 s1 = *(const float4*)(S1 + b * NCL + k);
    float c0 = 1.f / (s1.x + 1e-8f), c1 = 1.f / (s1.y + 1e-8f);
    float c2 = 1.f / (s1.z + 1e-8f), c3 = 1.f / (s1.w + 1e-8f);
    if (nS >= 2) {
      float4 s2 = *(const float4*)(S2 + b * NCL + k);
      c0 = c0 / (c0 * s2.x + 1e-8f); c1 = c1 / (c1 * s2.y + 1e-8f);
      c2 = c2 / (c2 * s2.z + 1e-8f); c3 = c3 / (c3 * s2.w + 1e-8f);
    }
    if (nS >= 3) {
      float4 s3 = *(const float4*)(S3 + b * NCL + k);
      c0 = c0 / (c0 * s3.x + 1e-8f); c1 = c1 / (c1 * s3.y + 1e-8f);
      c2 = c2 / (c2 * s3.z + 1e-8f); c3 = c3 / (c3 * s3.w + 1e-8f);
    }
    cs[k] = c0; cs[k + 1] = c1; cs[k + 2] = c2; cs[k + 3] = c3;
  }
  __syncthreads();
  const int wave = t >> 6, lane = t & 63;
  const int row0 = b * HWDIM + rc * 64;
  for (int rr = wave; rr < 64; rr += 4) {
    const int row = row0 + rr;
    const unsigned short* ep = E + (size_t)row * NCL + lane * 16;
    u16x8 e0 = *(const u16x8*)ep;
    u16x8 e1 = *(const u16x8*)(ep + 8);
    const float* cp = cs + lane * 16;
    float sum = 0.f;
#pragma unroll
    for (int j = 0; j < 8; j++) sum += bf2f(e0[j]) * cp[j];
#pragma unroll
    for (int j = 0; j < 8; j++) sum += bf2f(e1[j]) * cp[8 + j];
    for (int o = 32; o > 0; o >>= 1) sum += __shfl_xor(sum, o);
    if (lane == 0) {
      Tout[row] = sum;
      if (nS < 3) {
        float r;
        if (nS == 1) {
          r = 1.f / (sum + 1e-8f);
        } else {  // nS == 2
          r = 1.f / (T1p[row] + 1e-8f);
          r = r / (r * sum + 1e-8f);
        }
        rr_s[rr] = r;
      }
    }
  }
  if (nS >= 3) return;
  __syncthreads();
  float a0 = 0, a1 = 0, a2 = 0, a3 = 0;
  const unsigned short* basep = E + (size_t)row0 * NCL + t * 4;
  for (int rr = 0; rr < 64; ++rr) {
    const float rv = rr_s[rr];
    u16x4 ev = *(const u16x4*)(basep + (size_t)rr * NCL);
    a0 += bf2f(ev[0]) * rv; a1 += bf2f(ev[1]) * rv;
    a2 += bf2f(ev[2]) * rv; a3 += bf2f(ev[3]) * rv;
  }
  float* d = Sout + b * NCL + t * 4;
  atomicAdd(d + 0, a0); atomicAdd(d + 1, a1);
  atomicAdd(d + 2, a2); atomicAdd(d + 3, a3);
  (void)T2p;
}

// ---------- 6) final: assignments (in-place over logits) + loss ----------
__global__ __launch_bounds__(256) void final_kernel(
    float* __restrict__ IO, const unsigned* __restrict__ sk,
    const float* __restrict__ S1, const float* __restrict__ S2,
    const float* __restrict__ S3, const float* __restrict__ T1,
    const float* __restrict__ T2, const float* __restrict__ T3,
    float* __restrict__ lossout) {
  __shared__ float cs[NCL];
  __shared__ float offs[NCL];
  __shared__ float lred[4];
  const int b = blockIdx.x >> 4, rc = blockIdx.x & 15, t = threadIdx.x;
  {
    const int k = t * 4;
    float4 s1 = *(const float4*)(S1 + b * NCL + k);
    float4 s2 = *(const float4*)(S2 + b * NCL + k);
    float4 s3 = *(const float4*)(S3 + b * NCL + k);
    float c;
    c = 1.f / (s1.x + 1e-8f); c = c / (c * s2.x + 1e-8f); c = c / (c * s3.x + 1e-8f); cs[k] = c;
    c = 1.f / (s1.y + 1e-8f); c = c / (c * s2.y + 1e-8f); c = c / (c * s3.y + 1e-8f); cs[k + 1] = c;
    c = 1.f / (s1.z + 1e-8f); c = c / (c * s2.z + 1e-8f); c = c / (c * s3.z + 1e-8f); cs[k + 2] = c;
    c = 1.f / (s1.w + 1e-8f); c = c / (c * s2.w + 1e-8f); c = c / (c * s3.w + 1e-8f); cs[k + 3] = c;
    const unsigned* kp = sk + b * NCL + k;
    offs[k]     = 50.f - funkey(kp[0]) * INV_TT;
    offs[k + 1] = 50.f - funkey(kp[1]) * INV_TT;
    offs[k + 2] = 50.f - funkey(kp[2]) * INV_TT;
    offs[k + 3] = 50.f - funkey(kp[3]) * INV_TT;
  }
  __syncthreads();
  const int wave = t >> 6, lane = t & 63;
  float wsum = 0.f;
  for (int rr = wave; rr < 64; rr += 4) {
    const int row = b * HWDIM + rc * 64 + rr;
    float r3;
    {
      float r = 1.f / (T1[row] + 1e-8f);
      r = r / (r * T2[row] + 1e-8f);
      r = r / (r * T3[row] + 1e-8f);
      r3 = r;
    }
    float* p = IO + (size_t)row * NCL + lane * 16;
    float4 v0 = *(const float4*)(p);
    float4 v1 = *(const float4*)(p + 4);
    float4 v2 = *(const float4*)(p + 8);
    float4 v3 = *(const float4*)(p + 12);
    float lv[16] = {v0.x, v0.y, v0.z, v0.w, v1.x, v1.y, v1.z, v1.w,
                    v2.x, v2.y, v2.z, v2.w, v3.x, v3.y, v3.z, v3.w};
    float mx = lv[0];
#pragma unroll
    for (int j = 1; j < 16; j++) mx = fmaxf(mx, lv[j]);
    for (int o = 32; o > 0; o >>= 1) mx = fmaxf(mx, __shfl_xor(mx, o));
    const float mp = mx * INV_PT;
    float esum = 0.f, tp = 0.f, ts = 0.f;
    float tg[16];
    const float* cp = cs + lane * 16;
    const float* op = offs + lane * 16;
#pragma unroll
    for (int j = 0; j < 16; j++) {
      const float Ev = __expf(lv[j] * INV_TT + op[j]);
      const float g = Ev * cp[j] * r3;
      tg[j] = g;
      const float pd = lv[j] * INV_PT;
      esum += __expf(pd - mp);
      tp += g * pd;
      ts += g;
    }
    for (int o = 32; o > 0; o >>= 1) {
      esum += __shfl_xor(esum, o);
      tp += __shfl_xor(tp, o);
      ts += __shfl_xor(ts, o);
    }
    if (lane == 0) wsum += tp - (mp + logf(esum)) * ts;
    float4 w0 = {tg[0], tg[1], tg[2], tg[3]};
    float4 w1 = {tg[4], tg[5], tg[6], tg[7]};
    float4 w2 = {tg[8], tg[9], tg[10], tg[11]};
    float4 w3 = {tg[12], tg[13], tg[14], tg[15]};
    *(float4*)(p) = w0;
    *(float4*)(p + 4) = w1;
    *(float4*)(p + 8) = w2;
    *(float4*)(p + 12) = w3;
  }
  if (lane == 0) lred[wave] = wsum;
  __syncthreads();
  if (t == 0) {
    const float bl = lred[0] + lred[1] + lred[2] + lred[3];
    atomicAdd(lossout, bl * (-1.f / 32768.f));
  }
}

// ---------- launch ----------
extern "C" void kernel_launch(void* const* d_in, const int* in_sizes, int n_in,
                              void* d_out, int out_size, void* d_ws, size_t ws_size,
                              hipStream_t stream) {
  const float* x = (const float*)d_in[0];
  const float* W = (const float*)d_in[1];
  float* out = (float*)d_out;
  char* ws = (char*)d_ws;

  const size_t MiB = 1024 * 1024;
  unsigned short* Ahi = (unsigned short*)(ws);                 // 64 MiB
  unsigned short* Alo = (unsigned short*)(ws + 64 * MiB);      // 64 MiB
  unsigned short* Bhi = (unsigned short*)(ws + 128 * MiB);     // 2 MiB
  unsigned short* Blo = (unsigned short*)(ws + 130 * MiB);     // 2 MiB
  unsigned short* E   = (unsigned short*)(ws);                 // aliases Ahi (dead after GEMM)
  char* small = ws + 132 * MiB;
  unsigned* sk = (unsigned*)(small);                           // 128 KiB (zero = -inf key)
  float* S1 = (float*)(small + 128 * 1024);
  float* S2 = (float*)(small + 256 * 1024);
  float* S3 = (float*)(small + 384 * 1024);
  float* T1 = (float*)(small + 512 * 1024);
  float* T2 = (float*)(small + 640 * 1024);
  float* T3 = (float*)(small + 768 * 1024);

  float* logits = out;               // first 33554432 floats of d_out used as scratch
  float* lossp = out + 33554432;

  hipMemsetAsync(small, 0, 896 * 1024, stream);
  hipMemsetAsync(lossp, 0, 4, stream);

  normx_kernel<<<MROWS, 256, 0, stream>>>(x, Ahi, Alo);
  convw_kernel<<<NCL, 256, 0, stream>>>(W, Bhi, Blo);
  gemm_kernel<<<512, 512, 0, stream>>>(Ahi, Alo, Bhi, Blo, logits, sk);
  expcs_kernel<<<512, 256, 0, stream>>>(logits, sk, E, S1);
  fused_ts_kernel<<<512, 256, 0, stream>>>(E, S1, S2, S3, T1, T2, 1, T1, S2);
  fused_ts_kernel<<<512, 256, 0, stream>>>(E, S1, S2, S3, T1, T2, 2, T2, S3);
  fused_ts_kernel<<<512, 256, 0, stream>>>(E, S1, S2, S3, T1, T2, 3, T3, nullptr);
  final_kernel<<<512, 256, 0, stream>>>(logits, sk, S1, S2, S3, T1, T2, T3, lossp);
}

// Round 5
// 563.442 us; speedup vs baseline: 1.0511x; 1.0036x over previous
//
#include <hip/hip_runtime.h>
#include <cstdint>
#include <cstddef>

#define BATCH 32
#define HWDIM 1024
#define MROWS 32768   // BATCH*HWDIM
#define CDIM  1024    // feature dim
#define NCL   1024    // clusters

#define INV_TT 16.6666666f   // 1/0.06
#define INV_PT 8.33333333f   // 1/0.12

typedef __attribute__((ext_vector_type(8))) short bf16x8;
typedef __attribute__((ext_vector_type(4))) float f32x4;
typedef __attribute__((ext_vector_type(8))) unsigned short u16x8;
typedef __attribute__((ext_vector_type(4))) unsigned short u16x4;

// ---------- helpers ----------
__device__ __forceinline__ unsigned short f2bf(float f) {
  unsigned u = __float_as_uint(f);
  unsigned r = u + 0x7fffu + ((u >> 16) & 1u);   // round-to-nearest-even
  return (unsigned short)(r >> 16);
}
__device__ __forceinline__ float bf2f(unsigned short h) {
  return __uint_as_float(((unsigned)h) << 16);
}
// order-preserving float->uint key for atomicMax on floats (0 acts as -inf)
__device__ __forceinline__ unsigned fkey(float f) {
  unsigned u = __float_as_uint(f);
  return (u & 0x80000000u) ? ~u : (u | 0x80000000u);
}
__device__ __forceinline__ float funkey(unsigned k) {
  unsigned u = (k & 0x80000000u) ? (k & 0x7fffffffu) : ~k;
  return __uint_as_float(u);
}
__device__ __forceinline__ void async16(const unsigned short* g, unsigned short* l) {
  __builtin_amdgcn_global_load_lds(
      (const __attribute__((address_space(1))) unsigned int*)g,
      (__attribute__((address_space(3))) unsigned int*)l, 16, 0, 0);
}
__device__ __forceinline__ f32x4 mfma16(bf16x8 a, bf16x8 b, f32x4 c) {
  return __builtin_amdgcn_mfma_f32_16x16x32_bf16(a, b, c, 0, 0, 0);
}

#define BARX()   __builtin_amdgcn_s_barrier()
#define SCHED0() __builtin_amdgcn_sched_barrier(0)
#define VMCNT0() asm volatile("s_waitcnt vmcnt(0)" ::: "memory")
#define VMCNT8() asm volatile("s_waitcnt vmcnt(8)" ::: "memory")
#define LGKM0()  asm volatile("s_waitcnt lgkmcnt(0)" ::: "memory")

// ---------- 1) normalize x rows, emit split-bf16 ----------
// one wave per row: no LDS, no __syncthreads; lane holds 16 consecutive
// floats via 4x float4 at (lane + 64*i)*4 -> each load instr covers a
// contiguous 1 KiB across the wave.
__global__ __launch_bounds__(256) void normx_kernel(
    const float* __restrict__ x, unsigned short* __restrict__ Ahi,
    unsigned short* __restrict__ Alo) {
  const int wave = threadIdx.x >> 6, lane = threadIdx.x & 63;
  const int row = blockIdx.x * 4 + wave;          // 8192 blocks
  const float* xr = x + (size_t)row * CDIM;
  float4 v[4];
  float ss = 0.f;
#pragma unroll
  for (int i = 0; i < 4; i++) {
    v[i] = *(const float4*)(xr + (lane + 64 * i) * 4);
    ss += v[i].x * v[i].x + v[i].y * v[i].y + v[i].z * v[i].z + v[i].w * v[i].w;
  }
  for (int o = 32; o > 0; o >>= 1) ss += __shfl_xor(ss, o);
  const float inv = 1.0f / fmaxf(sqrtf(ss), 1e-7f);
#pragma unroll
  for (int i = 0; i < 4; i++) {
    const float f0 = v[i].x * inv, f1 = v[i].y * inv;
    const float f2 = v[i].z * inv, f3 = v[i].w * inv;
    u16x4 hi, lo;
    hi[0] = f2bf(f0); lo[0] = f2bf(f0 - bf2f(hi[0]));
    hi[1] = f2bf(f1); lo[1] = f2bf(f1 - bf2f(hi[1]));
    hi[2] = f2bf(f2); lo[2] = f2bf(f2 - bf2f(hi[2]));
    hi[3] = f2bf(f3); lo[3] = f2bf(f3 - bf2f(hi[3]));
    *(u16x4*)(Ahi + (size_t)row * CDIM + (lane + 64 * i) * 4) = hi;
    *(u16x4*)(Alo + (size_t)row * CDIM + (lane + 64 * i) * 4) = lo;
  }
}

// ---------- 2) split W into bf16 hi/lo ----------
__global__ __launch_bounds__(256) void convw_kernel(
    const float* __restrict__ Wm, unsigned short* __restrict__ Bhi,
    unsigned short* __restrict__ Blo) {
  const int row = blockIdx.x;
  const int t = threadIdx.x;
  const float4 v = *(const float4*)(Wm + (size_t)row * CDIM + t * 4);
  u16x4 hi, lo;
  hi[0] = f2bf(v.x); lo[0] = f2bf(v.x - bf2f(hi[0]));
  hi[1] = f2bf(v.y); lo[1] = f2bf(v.y - bf2f(hi[1]));
  hi[2] = f2bf(v.z); lo[2] = f2bf(v.z - bf2f(hi[2]));
  hi[3] = f2bf(v.w); lo[3] = f2bf(v.w - bf2f(hi[3]));
  *(u16x4*)(Bhi + (size_t)row * CDIM + t * 4) = hi;
  *(u16x4*)(Blo + (size_t)row * CDIM + t * 4) = lo;
}

// ---------- 3) split-bf16 GEMM + fused per-batch column max ----------
// 256x256 tile, BK=32, 8 waves (2m x 4n), per-wave 128x64, 3 MFMAs (hh+hl+lh).
// T3+T4: 4-phase K-step with COUNTED vmcnt (2-deep prefetch):
//   A ring 3-deep (96 KiB), B ring 2-deep (64 KiB) = 160 KiB LDS.
//   step t p0: issue A(t+2); p1: issue B(t+2); p3 end: vmcnt(8).
// LDS chunk-rotation swizzle (0-conflict, proven); pre-swizzled GLOBAL
// source, linear LDS dest. XCD swizzle: nt fastest -> A-panel L2 reuse.
__global__ __launch_bounds__(512, 2) void gemm_kernel(
    const unsigned short* __restrict__ Ahi, const unsigned short* __restrict__ Alo,
    const unsigned short* __restrict__ Bhi, const unsigned short* __restrict__ Blo,
    float* __restrict__ C, unsigned* __restrict__ sk) {
  __shared__ unsigned short sAhi[3][8192], sAlo[3][8192];
  __shared__ unsigned short sBhi[2][8192], sBlo[2][8192];

  const int l = blockIdx.x;                 // 0..511
  const int idx = (l & 7) * 64 + (l >> 3);  // xcd-contiguous chunk
  const int m0 = (idx >> 2) * 256;          // 128 m-tiles
  const int n0 = (idx & 3) * 256;           // 4 n-tiles (fastest)
  const int tid = threadIdx.x;
  const int wave = tid >> 6;
  const int lane = tid & 63;
  const int fl = lane & 15;   // fragment row/col
  const int q = lane >> 4;    // quad: k-offset q*8 (inputs), row-offset q*4 (C/D)
  const int wr = (wave >> 2) * 128;   // 0 or 128
  const int wc = (wave & 3) * 64;     // 0,64,128,192

  // staging coords: thread fills 16B phys slot (tid&3) of local row (tid>>2)
  const int srow = tid >> 2;          // 0..127
  const int pph = tid & 3;
  const int r0 = srow, r1 = 128 + srow;
  const int j0 = (pph - (r0 >> 1)) & 3;   // logical chunk at my phys slot
  const int j1 = (pph - (r1 >> 1)) & 3;
  const size_t aoff0 = (size_t)(m0 + r0) * CDIM + j0 * 8;
  const size_t aoff1 = (size_t)(m0 + r1) * CDIM + j1 * 8;
  const size_t boff0 = (size_t)(n0 + r0) * CDIM + j0 * 8;
  const size_t boff1 = (size_t)(n0 + r1) * CDIM + j1 * 8;
  const int ld0 = (0 + (wave << 4)) * 32;    // wave-uniform LDS dest (rows 0-127)
  const int ld1 = (128 + (wave << 4)) * 32;  // rows 128-255

  f32x4 acc[8][4];
#pragma unroll
  for (int i = 0; i < 8; i++)
#pragma unroll
    for (int j = 0; j < 4; j++) { f32x4 z = {0.f, 0.f, 0.f, 0.f}; acc[i][j] = z; }

#define STAGE_A(k, b) do {                           \
    async16(Ahi + aoff0 + (k), &sAhi[b][ld0]);       \
    async16(Alo + aoff0 + (k), &sAlo[b][ld0]);       \
    async16(Ahi + aoff1 + (k), &sAhi[b][ld1]);       \
    async16(Alo + aoff1 + (k), &sAlo[b][ld1]);       \
  } while (0)
#define STAGE_B(k, b) do {                           \
    async16(Bhi + boff0 + (k), &sBhi[b][ld0]);       \
    async16(Blo + boff0 + (k), &sBlo[b][ld0]);       \
    async16(Bhi + boff1 + (k), &sBhi[b][ld1]);       \
    async16(Blo + boff1 + (k), &sBlo[b][ld1]);       \
  } while (0)

  // rows ra0 and ra0+16 share the phys rotation ((r>>1) differs by 8 == 0 mod 4)
#define READ_A(p) do {                                   \
    const int ra0 = wr + 2 * (p) * 16 + fl;              \
    const int pa0 = ((q + (ra0 >> 1)) & 3) * 8;          \
    ah0 = *(const bf16x8*)&sAhi[ca][ra0 * 32 + pa0];     \
    al0 = *(const bf16x8*)&sAlo[ca][ra0 * 32 + pa0];     \
    const int ra1 = ra0 + 16;                            \
    ah1 = *(const bf16x8*)&sAhi[ca][ra1 * 32 + pa0];     \
    al1 = *(const bf16x8*)&sAlo[ca][ra1 * 32 + pa0];     \
  } while (0)

#define MFMA_P(p) do {                                             \
    __builtin_amdgcn_s_setprio(1);                                 \
    _Pragma("unroll")                                              \
    for (int nj = 0; nj < 4; ++nj) {                               \
      acc[2*(p)][nj]   = mfma16(ah0, bh[nj], acc[2*(p)][nj]);      \
      acc[2*(p)][nj]   = mfma16(ah0, bl[nj], acc[2*(p)][nj]);      \
      acc[2*(p)][nj]   = mfma16(al0, bh[nj], acc[2*(p)][nj]);      \
      acc[2*(p)+1][nj] = mfma16(ah1, bh[nj], acc[2*(p)+1][nj]);    \
      acc[2*(p)+1][nj] = mfma16(ah1, bl[nj], acc[2*(p)+1][nj]);    \
      acc[2*(p)+1][nj] = mfma16(al1, bh[nj], acc[2*(p)+1][nj]);    \
    }                                                              \
    __builtin_amdgcn_s_setprio(0);                                 \
  } while (0)

  // prologue: stage steps 0 and 1; wait only for step 0 (vmcnt(8))
  STAGE_A((size_t)0, 0);
  STAGE_B((size_t)0, 0);
  STAGE_A((size_t)32, 1);
  STAGE_B((size_t)32, 1);
  VMCNT8();
  BARX();

  bf16x8 bh[4], bl[4], ah0, al0, ah1, al1;
  int ca = 0;   // A buf for step t   (t % 3)
  int pa = 2;   // A buf for step t+2 ((t+2) % 3)

  for (int t = 0; t < 32; ++t) {
    const int cb = t & 1;               // B buf for step t (and dest for t+2)

    // ---- phase 0: B frags + A pair0; prefetch A(t+2) ----
#pragma unroll
    for (int nj = 0; nj < 4; ++nj) {
      const int rb = wc + nj * 16 + fl;
      const int pb = ((q + (rb >> 1)) & 3) * 8;
      bh[nj] = *(const bf16x8*)&sBhi[cb][rb * 32 + pb];
      bl[nj] = *(const bf16x8*)&sBlo[cb][rb * 32 + pb];
    }
    READ_A(0);
    if (t < 30) {
      const size_t kn = (size_t)(t + 2) * 32;
      STAGE_A(kn, pa);
    }
    BARX(); LGKM0(); SCHED0();
    MFMA_P(0);
    BARX();
    // ---- phase 1: prefetch B(t+2) (Bbuf[cb] freed by phase-0 barrier) ----
    READ_A(1);
    if (t < 30) {
      const size_t kn = (size_t)(t + 2) * 32;
      STAGE_B(kn, cb);
    }
    BARX(); LGKM0(); SCHED0();
    MFMA_P(1);
    BARX();
    // ---- phase 2 ----
    READ_A(2);
    BARX(); LGKM0(); SCHED0();
    MFMA_P(2);
    BARX();
    // ---- phase 3 ----
    READ_A(3);
    BARX(); LGKM0(); SCHED0();
    MFMA_P(3);
    if (t < 30) VMCNT8();   // counted: step t+2 loads stay in flight
    else        VMCNT0();   // tail drain
    BARX();

    ca = (ca == 2) ? 0 : ca + 1;
    pa = (pa == 2) ? 0 : pa + 1;
  }

  // fused column max of this tile (per batch); 256-row tile is within one batch
  const int batch = m0 >> 10;
#pragma unroll
  for (int nj = 0; nj < 4; ++nj) {
    float m = -3.4e38f;
#pragma unroll
    for (int mi = 0; mi < 8; ++mi)
#pragma unroll
      for (int r = 0; r < 4; ++r) m = fmaxf(m, acc[mi][nj][r]);
    m = fmaxf(m, __shfl_xor(m, 16));
    m = fmaxf(m, __shfl_xor(m, 32));
    if (q == 0) atomicMax(&sk[batch * NCL + n0 + wc + nj * 16 + fl], fkey(m));
  }

  // epilogue: C/D layout col=lane&15, row=q*4+reg
#pragma unroll
  for (int mi = 0; mi < 8; ++mi)
#pragma unroll
    for (int nj = 0; nj < 4; ++nj)
#pragma unroll
      for (int r = 0; r < 4; ++r) {
        const int gm = m0 + wr + mi * 16 + q * 4 + r;
        const int gn = n0 + wc + nj * 16 + fl;
        C[(size_t)gm * NCL + gn] = acc[mi][nj][r];
      }
#undef STAGE_A
#undef STAGE_B
#undef READ_A
#undef MFMA_P
}

// ---------- 4) E = exp(l/0.06 + 50 - shift) -> bf16; S1 = colsum(E) ----------
__global__ __launch_bounds__(256) void expcs_kernel(
    const float* __restrict__ L, const unsigned* __restrict__ sk,
    unsigned short* __restrict__ E, float* __restrict__ S1) {
  const int b = blockIdx.x >> 4, rc = blockIdx.x & 15, t = threadIdx.x;
  const size_t base = ((size_t)b * HWDIM + rc * 64) * NCL + t * 4;
  const unsigned* kp = sk + b * NCL + t * 4;
  const float o0 = 50.f - funkey(kp[0]) * INV_TT;
  const float o1 = 50.f - funkey(kp[1]) * INV_TT;
  const float o2 = 50.f - funkey(kp[2]) * INV_TT;
  const float o3 = 50.f - funkey(kp[3]) * INV_TT;
  float s0 = 0, s1 = 0, s2 = 0, s3 = 0;
  for (int r = 0; r < 64; ++r) {
    float4 v = *(const float4*)(L + base + (size_t)r * NCL);
    float e0 = __expf(v.x * INV_TT + o0);
    float e1 = __expf(v.y * INV_TT + o1);
    float e2 = __expf(v.z * INV_TT + o2);
    float e3 = __expf(v.w * INV_TT + o3);
    s0 += e0; s1 += e1; s2 += e2; s3 += e3;
    u16x4 ev; ev[0] = f2bf(e0); ev[1] = f2bf(e1); ev[2] = f2bf(e2); ev[3] = f2bf(e3);
    *(u16x4*)(E + base + (size_t)r * NCL) = ev;
  }
  float* d = S1 + b * NCL + t * 4;
  atomicAdd(d + 0, s0); atomicAdd(d + 1, s1);
  atomicAdd(d + 2, s2); atomicAdd(d + 3, s3);
}

// ---------- 5) fused T_i (row sums) + S_{i+1} (col sums) ----------
__global__ __launch_bounds__(256) void fused_ts_kernel(
    const unsigned short* __restrict__ E, const float* __restrict__ S1,
    const float* __restrict__ S2, const float* __restrict__ S3,
    const float* __restrict__ T1p, const float* __restrict__ T2p, int nS,
    float* __restrict__ Tout, float* __restrict__ Sout) {
  __shared__ float cs[NCL];
  __shared__ float rr_s[64];
  const int b = blockIdx.x >> 4, rc = blockIdx.x & 15, t = threadIdx.x;
  {
    const int k = t * 4;
    float4 s1 = *(const float4*)(S1 + b * NCL + k);
    float c0 = 1.f / (s1.x + 1e-8f), c1 = 1.f / (s1.y + 1e-8f);
    float c2 = 1.f / (s1.z + 1e-8f), c3 = 1.f / (s1.w + 1e-8f);
    if (nS >= 2) {
      float4 s2 = *(const float4*)(S2 + b * NCL + k);
      c0 = c0 / (c0 * s2.x + 1e-8f); c1 = c1 / (c1 * s2.y + 1e-8f);
      c2 = c2 / (c2 * s2.z + 1e-8f); c3 = c3 / (c3 * s2.w + 1e-8f);
    }
    if (nS >= 3) {
      float4 s3 = *(const float4*)(S3 + b * NCL + k);
      c0 = c0 / (c0 * s3.x + 1e-8f); c1 = c1 / (c1 * s3.y + 1e-8f);
      c2 = c2 / (c2 * s3.z + 1e-8f); c3 = c3 / (c3 * s3.w + 1e-8f);
    }
    cs[k] = c0; cs[k + 1] = c1; cs[k + 2] = c2; cs[k + 3] = c3;
  }
  __syncthreads();
  const int wave = t >> 6, lane = t & 63;
  const int row0 = b * HWDIM + rc * 64;
  for (int rr = wave; rr < 64; rr += 4) {
    const int row = row0 + rr;
    const unsigned short* ep = E + (size_t)row * NCL + lane * 16;
    u16x8 e0 = *(const u16x8*)ep;
    u16x8 e1 = *(const u16x8*)(ep + 8);
    const float* cp = cs + lane * 16;
    float sum = 0.f;
#pragma unroll
    for (int j = 0; j < 8; j++) sum += bf2f(e0[j]) * cp[j];
#pragma unroll
    for (int j = 0; j < 8; j++) sum += bf2f(e1[j]) * cp[8 + j];
    for (int o = 32; o > 0; o >>= 1) sum += __shfl_xor(sum, o);
    if (lane == 0) {
      Tout[row] = sum;
      if (nS < 3) {
        float r;
        if (nS == 1) {
          r = 1.f / (sum + 1e-8f);
        } else {  // nS == 2
          r = 1.f / (T1p[row] + 1e-8f);
          r = r / (r * sum + 1e-8f);
        }
        rr_s[rr] = r;
      }
    }
  }
  if (nS >= 3) return;
  __syncthreads();
  float a0 = 0, a1 = 0, a2 = 0, a3 = 0;
  const unsigned short* basep = E + (size_t)row0 * NCL + t * 4;
  for (int rr = 0; rr < 64; ++rr) {
    const float rv = rr_s[rr];
    u16x4 ev = *(const u16x4*)(basep + (size_t)rr * NCL);
    a0 += bf2f(ev[0]) * rv; a1 += bf2f(ev[1]) * rv;
    a2 += bf2f(ev[2]) * rv; a3 += bf2f(ev[3]) * rv;
  }
  float* d = Sout + b * NCL + t * 4;
  atomicAdd(d + 0, a0); atomicAdd(d + 1, a1);
  atomicAdd(d + 2, a2); atomicAdd(d + 3, a3);
  (void)T2p;
}

// ---------- 6) final: assignments (in-place over logits) + loss ----------
// T3 folded in: each wave holds its full row, so T3raw = rowsum(Ev*c123) = se
// via wave-reduce; r3 = r12/(r12*se + eps) -- same chain as the old ts3+final.
__global__ __launch_bounds__(256) void final_kernel(
    float* __restrict__ IO, const unsigned* __restrict__ sk,
    const float* __restrict__ S1, const float* __restrict__ S2,
    const float* __restrict__ S3, const float* __restrict__ T1,
    const float* __restrict__ T2, float* __restrict__ lossout) {
  __shared__ float cs[NCL];
  __shared__ float offs[NCL];
  __shared__ float lred[4];
  const int b = blockIdx.x >> 4, rc = blockIdx.x & 15, t = threadIdx.x;
  {
    const int k = t * 4;
    float4 s1 = *(const float4*)(S1 + b * NCL + k);
    float4 s2 = *(const float4*)(S2 + b * NCL + k);
    float4 s3 = *(const float4*)(S3 + b * NCL + k);
    float c;
    c = 1.f / (s1.x + 1e-8f); c = c / (c * s2.x + 1e-8f); c = c / (c * s3.x + 1e-8f); cs[k] = c;
    c = 1.f / (s1.y + 1e-8f); c = c / (c * s2.y + 1e-8f); c = c / (c * s3.y + 1e-8f); cs[k + 1] = c;
    c = 1.f / (s1.z + 1e-8f); c = c / (c * s2.z + 1e-8f); c = c / (c * s3.z + 1e-8f); cs[k + 2] = c;
    c = 1.f / (s1.w + 1e-8f); c = c / (c * s2.w + 1e-8f); c = c / (c * s3.w + 1e-8f); cs[k + 3] = c;
    const unsigned* kp = sk + b * NCL + k;
    offs[k]     = 50.f - funkey(kp[0]) * INV_TT;
    offs[k + 1] = 50.f - funkey(kp[1]) * INV_TT;
    offs[k + 2] = 50.f - funkey(kp[2]) * INV_TT;
    offs[k + 3] = 50.f - funkey(kp[3]) * INV_TT;
  }
  __syncthreads();
  const int wave = t >> 6, lane = t & 63;
  float wsum = 0.f;
  for (int rr = wave; rr < 64; rr += 4) {
    const int row = b * HWDIM + rc * 64 + rr;
    float r12;
    {
      float r = 1.f / (T1[row] + 1e-8f);
      r = r / (r * T2[row] + 1e-8f);
      r12 = r;
    }
    float* p = IO + (size_t)row * NCL + lane * 16;
    float4 v0 = *(const float4*)(p);
    float4 v1 = *(const float4*)(p + 4);
    float4 v2 = *(const float4*)(p + 8);
    float4 v3 = *(const float4*)(p + 12);
    float lv[16] = {v0.x, v0.y, v0.z, v0.w, v1.x, v1.y, v1.z, v1.w,
                    v2.x, v2.y, v2.z, v2.w, v3.x, v3.y, v3.z, v3.w};
    float mx = lv[0];
#pragma unroll
    for (int j = 1; j < 16; j++) mx = fmaxf(mx, lv[j]);
    for (int o = 32; o > 0; o >>= 1) mx = fmaxf(mx, __shfl_xor(mx, o));
    const float mp = mx * INV_PT;
    float esum = 0.f, se = 0.f, sp = 0.f;
    float ec[16];
    const float* cp = cs + lane * 16;
    const float* op = offs + lane * 16;
#pragma unroll
    for (int j = 0; j < 16; j++) {
      const float Ev = __expf(lv[j] * INV_TT + op[j]);
      const float e = Ev * cp[j];    // E * c1c2c3
      ec[j] = e;
      const float pd = lv[j] * INV_PT;
      esum += __expf(pd - mp);
      se += e;
      sp += e * pd;
    }
    for (int o = 32; o > 0; o >>= 1) {
      esum += __shfl_xor(esum, o);
      se += __shfl_xor(se, o);
      sp += __shfl_xor(sp, o);
    }
    // se == T3raw (rowsum of E*c123); chained row scale r3 = r12/(r12*T3raw+eps)
    const float r3 = r12 / (r12 * se + 1e-8f);
    if (lane == 0) wsum += r3 * sp - (mp + logf(esum)) * (r3 * se);
    float4 w0 = {ec[0] * r3, ec[1] * r3, ec[2] * r3, ec[3] * r3};
    float4 w1 = {ec[4] * r3, ec[5] * r3, ec[6] * r3, ec[7] * r3};
    float4 w2 = {ec[8] * r3, ec[9] * r3, ec[10] * r3, ec[11] * r3};
    float4 w3 = {ec[12] * r3, ec[13] * r3, ec[14] * r3, ec[15] * r3};
    *(float4*)(p) = w0;
    *(float4*)(p + 4) = w1;
    *(float4*)(p + 8) = w2;
    *(float4*)(p + 12) = w3;
  }
  if (lane == 0) lred[wave] = wsum;
  __syncthreads();
  if (t == 0) {
    const float bl = lred[0] + lred[1] + lred[2] + lred[3];
    atomicAdd(lossout, bl * (-1.f / 32768.f));
  }
}

// ---------- launch ----------
extern "C" void kernel_launch(void* const* d_in, const int* in_sizes, int n_in,
                              void* d_out, int out_size, void* d_ws, size_t ws_size,
                              hipStream_t stream) {
  const float* x = (const float*)d_in[0];
  const float* W = (const float*)d_in[1];
  float* out = (float*)d_out;
  char* ws = (char*)d_ws;

  const size_t MiB = 1024 * 1024;
  unsigned short* Ahi = (unsigned short*)(ws);                 // 64 MiB
  unsigned short* Alo = (unsigned short*)(ws + 64 * MiB);      // 64 MiB
  unsigned short* Bhi = (unsigned short*)(ws + 128 * MiB);     // 2 MiB
  unsigned short* Blo = (unsigned short*)(ws + 130 * MiB);     // 2 MiB
  unsigned short* E   = (unsigned short*)(ws);                 // aliases Ahi (dead after GEMM)
  char* small = ws + 132 * MiB;
  unsigned* sk = (unsigned*)(small);                           // 128 KiB (zero = -inf key)
  float* S1 = (float*)(small + 128 * 1024);
  float* S2 = (float*)(small + 256 * 1024);
  float* S3 = (float*)(small + 384 * 1024);
  float* T1 = (float*)(small + 512 * 1024);
  float* T2 = (float*)(small + 640 * 1024);

  float* logits = out;               // first 33554432 floats of d_out used as scratch
  float* lossp = out + 33554432;

  hipMemsetAsync(small, 0, 896 * 1024, stream);
  hipMemsetAsync(lossp, 0, 4, stream);

  normx_kernel<<<8192, 256, 0, stream>>>(x, Ahi, Alo);
  convw_kernel<<<NCL, 256, 0, stream>>>(W, Bhi, Blo);
  gemm_kernel<<<512, 512, 0, stream>>>(Ahi, Alo, Bhi, Blo, logits, sk);
  expcs_kernel<<<512, 256, 0, stream>>>(logits, sk, E, S1);
  fused_ts_kernel<<<512, 256, 0, stream>>>(E, S1, S2, S3, T1, T2, 1, T1, S2);
  fused_ts_kernel<<<512, 256, 0, stream>>>(E, S1, S2, S3, T1, T2, 2, T2, S3);
  final_kernel<<<512, 256, 0, stream>>>(logits, sk, S1, S2, S3, T1, T2, lossp);
}